// Round 6
// baseline (4711.678 us; speedup 1.0000x reference)
//
#include <hip/hip_runtime.h>

#define BB 8
#define NN 8192
#define RR 2048
#define KK 4
#define LL 4
#define TC 61
#define EPSF 1e-6f
#define BN (BB*NN)
#define OUTN (BN*3)

typedef unsigned short u16;
typedef unsigned int u32;

__device__ __forceinline__ float bf2f(u16 h) { return __uint_as_float(((u32)h) << 16); }
__device__ __forceinline__ u16 f2bf(float f) {
  u32 u = __float_as_uint(f);
  u32 r = (u + 0x7fffu + ((u >> 16) & 1u)) >> 16;
  return (u16)r;
}
__device__ __forceinline__ float ldS(const float* p) { return *p; }
__device__ __forceinline__ float ldS(const u16* p) { return bf2f(*p); }
__device__ __forceinline__ void stS(float* p, float v) { *p = v; }
__device__ __forceinline__ void stS(u16* p, float v) { *p = f2bf(v); }

__device__ __forceinline__ int kmax_of(int n) {
  int aatom = n & 3, rres = n >> 2;
  return (aatom==0) ? (rres==0 ? 2 : 3)
       : (aatom==1) ? 3
       : (aatom==2) ? (rres==RR-1 ? 3 : 4) : 2;
}

// ---------------- input structural validation ----------------
__global__ __launch_bounds__(256) void k_check(const int* nbr, const void* maskp,
                                               const float* x, const float* t, int* diag) {
  __shared__ int s_nbrbad, s_u8bad, s_i32bad, s_xbad, s_tbad;
  if (threadIdx.x == 0) { s_nbrbad=0; s_u8bad=0; s_i32bad=0; s_xbad=0; s_tbad=0; }
  __syncthreads();
  const unsigned char* m8 = (const unsigned char*)maskp;
  const int* m32 = (const int*)maskp;
  for (int n = threadIdx.x; n < NN; n += 256) {
    if (nbr[n*4] != n) atomicOr(&s_nbrbad, 1);
    int km = kmax_of(n);
    for (int k = 0; k < 4; ++k) {
      bool want = (k < km);
      if ((m8[n*4+k]  != 0) != want) atomicOr(&s_u8bad, 1);
      if ((m32[n*4+k] != 0) != want) atomicOr(&s_i32bad, 1);
    }
  }
  for (int i = threadIdx.x; i < 1024; i += 256) {
    float v = x[i];
    if (!(v == v) || fabsf(v) > 1000.f) atomicOr(&s_xbad, 1);
  }
  if (threadIdx.x < 8) {
    float tv = t[threadIdx.x];
    if (!(tv >= 0.f && tv < 1.0001f)) atomicOr(&s_tbad, 1);
  }
  __syncthreads();
  if (threadIdx.x == 0) {
    int code = 0;
    if (s_nbrbad) code = 2000;
    else if (s_u8bad && s_i32bad) code = 2100;
    else if (s_xbad) code = 2200;
    else if (s_tbad) code = 2300;
    diag[0] = code;
  }
}

__global__ __launch_bounds__(256) void k_guard(const int* diag, float* out) {
  int code = diag[0];
  if (code == 0) return;
  int i = blockIdx.x*256 + threadIdx.x;
  if (i < OUTN) out[i] = (float)code;
}

__global__ __launch_bounds__(256) void k_const(float* out, float v) {
  int i = blockIdx.x*256 + threadIdx.x;
  if (i < OUTN) out[i] = v;
}

// ---------------- time embedding MLP ----------------
__global__ __launch_bounds__(128) void k_te(const float* t, const float* w1, const float* b1,
                                            const float* w2, const float* b2, float* te2) {
  __shared__ float s0[128], s1[128];
  int j = threadIdx.x;
  for (int b = 0; b < BB; ++b) {
    float tv = t[b];
    int i = j & 63;
    float fr = expf(-9.210340371976184f * (float)i * (1.0f/64.0f));
    float em = tv * fr;
    s0[j] = (j < 64) ? sinf(em) : cosf(em);
    __syncthreads();
    float acc = b1[j];
    for (int i2 = 0; i2 < 128; ++i2) acc += s0[i2] * w1[i2*128 + j];
    s1[j] = acc / (1.f + expf(-acc));
    __syncthreads();
    if (j < TC) {
      float a2 = b2[j];
      for (int i2 = 0; i2 < 128; ++i2) a2 += s1[i2] * w2[i2*TC + j];
      te2[b*TC + j] = a2;
    }
    __syncthreads();
  }
}

// ---------------- init ----------------
template<typename T>
__global__ __launch_bounds__(64) void k_init(const float* x, const float* win1, const int* nbr,
                                             const float* te2, T* f0, T* f1, float* rhat) {
  int tok = blockIdx.x, c = threadIdx.x;
  int b = tok >> 13, n = tok & (NN-1);
  float x0 = x[tok*3+0], x1 = x[tok*3+1], x2 = x[tok*3+2];
  stS(&f0[tok*64 + c], (c < TC) ? te2[b*TC + c] : (c == 61 ? x0 : (c == 62 ? x1 : x2)));
  float wv = win1[c];
  stS(&f1[(tok*3+0)*64 + c], x0 * wv);
  stS(&f1[(tok*3+1)*64 + c], x1 * wv);
  stS(&f1[(tok*3+2)*64 + c], x2 * wv);
  if (c < KK) {
    int tj = b*NN + nbr[n*KK + c];
    float rx = x[tj*3+0] - x0, ry = x[tj*3+1] - x1, rz = x[tj*3+2] - x2;
    float ir = rsqrtf(rx*rx + ry*ry + rz*rz + EPSF);
    rhat[(tok*KK+c)*3 + 0] = rx * ir;
    rhat[(tok*KK+c)*3 + 1] = ry * ir;
    rhat[(tok*KK+c)*3 + 2] = rz * ir;
  }
}

// ---------------- per-layer: normalize -> G (bf16) ----------------
template<typename T>
__global__ __launch_bounds__(64) void k_norm(const T* f0, const T* f1, u16* G0, u16* G1) {
  int tok = blockIdx.x, e = threadIdx.x;
  __shared__ float s_r0[64], s_r1[3][64];
  __shared__ float s_mu, s_ri, s_vs;
  s_r0[e] = ldS(&f0[tok*64 + e]);
  for (int v = 0; v < 3; ++v) s_r1[v][e] = ldS(&f1[(tok*3+v)*64 + e]);
  __syncthreads();
  if (e == 0) {
    float mu = 0.f;
    for (int c = 0; c < 64; ++c) mu += s_r0[c];
    mu *= (1.f/64.f);
    float var = 0.f;
    for (int c = 0; c < 64; ++c) { float d = s_r0[c] - mu; var += d*d; }
    float ss = 0.f;
    for (int c = 0; c < 64; ++c)
      ss += s_r1[0][c]*s_r1[0][c] + s_r1[1][c]*s_r1[1][c] + s_r1[2][c]*s_r1[2][c];
    s_mu = mu;
    s_ri = rsqrtf(var*(1.f/64.f) + EPSF);
    s_vs = rsqrtf(ss*(1.f/64.f) + EPSF);
  }
  __syncthreads();
  G0[tok*64 + e] = f2bf((s_r0[e] - s_mu) * s_ri);
  for (int v = 0; v < 3; ++v) G1[(tok*3+v)*64 + e] = f2bf(s_r1[v][e] * s_vs);
}

// ---------------- per-layer: fused qkv-recompute + attention + out-proj + residual ----------------
template<typename T>
__global__ __launch_bounds__(64) void k_attn(const u16* G0, const u16* G1,
    const float* wq0, const float* wk0, const float* wv0,
    const float* wq1, const float* wk1, const float* wv1,
    const float* wo0, const float* wo1, const int* nbr, const float* rhat,
    T* f0, T* f1) {
  int tok = blockIdx.x, e = threadIdx.x;
  int b = tok >> 13, n = tok & (NN-1);
  int km = kmax_of(n);
  __shared__ float s_gq0[64], s_gq1[3][64];
  __shared__ float s_gn0[4][64], s_gn1[4][3][64];
  __shared__ float s_q0[64], s_q1[3][64];
  __shared__ float s_k0[4][64], s_v0[4][64], s_k1[4][3][64], s_v1[4][3][64];
  __shared__ float s_rh[4][3], s_a[4][4];
  __shared__ float s_o0[64], s_o1[3][64];
  __shared__ int s_tk[4];
  if (e < 4) s_tk[e] = b*NN + nbr[n*4 + e];
  if (e < 12) s_rh[e/3][e%3] = rhat[tok*12 + e];
  __syncthreads();
  s_gq0[e] = bf2f(G0[tok*64+e]);
  for (int v = 0; v < 3; ++v) s_gq1[v][e] = bf2f(G1[(tok*3+v)*64+e]);
  for (int k = 0; k < 4; ++k) {
    int tj = s_tk[k];
    s_gn0[k][e] = bf2f(G0[tj*64+e]);
    for (int v = 0; v < 3; ++v) s_gn1[k][v][e] = bf2f(G1[(tj*3+v)*64+e]);
  }
  __syncthreads();
  float q0 = 0.f, q1[3] = {0,0,0};
  float k0[4] = {0,0,0,0}, v0[4] = {0,0,0,0};
  float k1[4][3] = {{0}}, v1[4][3] = {{0}};
  for (int c = 0; c < 64; ++c) {
    float wQ = wq0[c*64+e], wK = wk0[c*64+e], wV = wv0[c*64+e];
    float wQ1 = wq1[c*64+e], wK1 = wk1[c*64+e], wV1 = wv1[c*64+e];
    q0 += s_gq0[c] * wQ;
    for (int v = 0; v < 3; ++v) q1[v] += s_gq1[v][c] * wQ1;
    for (int k = 0; k < 4; ++k) {
      float g = s_gn0[k][c];
      k0[k] += g * wK;
      v0[k] += g * wV;
      for (int v = 0; v < 3; ++v) {
        float h = s_gn1[k][v][c];
        k1[k][v] += h * wK1;
        v1[k][v] += h * wV1;
      }
    }
  }
  s_q0[e] = q0;
  for (int v = 0; v < 3; ++v) s_q1[v][e] = q1[v];
  for (int k = 0; k < 4; ++k) {
    s_k0[k][e] = k0[k]; s_v0[k][e] = v0[k];
    for (int v = 0; v < 3; ++v) { s_k1[k][v][e] = k1[k][v]; s_v1[k][v][e] = v1[k][v]; }
  }
  __syncthreads();
  if (e < 4) {
    int h = e;
    float p[4];
    for (int k = 0; k < 4; ++k) {
      float acc = 0.f;
      for (int d = 0; d < 16; ++d) {
        int ee = h*16 + d;
        acc += s_q0[ee] * s_k0[k][ee];
        for (int v = 0; v < 3; ++v) acc += s_q1[v][ee] * s_k1[k][v][ee];
      }
      p[k] = acc * 0.25f;
    }
    float mx = -1e30f;
    for (int k = 0; k < km; ++k) mx = fmaxf(mx, p[k]);
    float aw[4], ss = 0.f;
    for (int k = 0; k < 4; ++k) { aw[k] = (k < km) ? expf(p[k]-mx) : 0.f; ss += aw[k]; }
    float inv = 1.f / ss;
    for (int k = 0; k < 4; ++k) s_a[h][k] = aw[k] * inv;
  }
  __syncthreads();
  {
    int h = e >> 4;
    float o0 = 0.f, o1[3] = {0,0,0};
    for (int k = 0; k < 4; ++k) {
      float a = s_a[h][k];
      float vdot = s_v1[k][0][e]*s_rh[k][0] + s_v1[k][1][e]*s_rh[k][1] + s_v1[k][2][e]*s_rh[k][2];
      o0 += a * (s_v0[k][e] + vdot);
      for (int v = 0; v < 3; ++v) o1[v] += a * (s_v1[k][v][e] + s_v0[k][e]*s_rh[k][v]);
    }
    s_o0[e] = o0;
    for (int v = 0; v < 3; ++v) s_o1[v][e] = o1[v];
  }
  __syncthreads();
  float acc0 = ldS(&f0[tok*64 + e]);
  float acc1[3];
  for (int v = 0; v < 3; ++v) acc1[v] = ldS(&f1[(tok*3+v)*64 + e]);
  for (int e2 = 0; e2 < 64; ++e2) {
    acc0 += s_o0[e2] * wo0[e2*64 + e];
    float w = wo1[e2*64 + e];
    for (int v = 0; v < 3; ++v) acc1[v] += s_o1[v][e2] * w;
  }
  stS(&f0[tok*64 + e], acc0);
  for (int v = 0; v < 3; ++v) stS(&f1[(tok*3+v)*64 + e], acc1[v]);
}

// ---------------- per-layer: scalar FF ----------------
template<typename T>
__global__ __launch_bounds__(64) void k_ff0(T* f0, const float* wa, const float* wb) {
  int tok = blockIdx.x, c = threadIdx.x;
  __shared__ float s_r[64], s_g[64], s_h[256];
  __shared__ float s_mu, s_ri;
  s_r[c] = ldS(&f0[tok*64 + c]);
  __syncthreads();
  if (c == 0) {
    float mu = 0.f;
    for (int i = 0; i < 64; ++i) mu += s_r[i];
    mu *= (1.f/64.f);
    float var = 0.f;
    for (int i = 0; i < 64; ++i) { float d = s_r[i] - mu; var += d*d; }
    s_mu = mu;
    s_ri = rsqrtf(var*(1.f/64.f) + EPSF);
  }
  __syncthreads();
  s_g[c] = (s_r[c] - s_mu) * s_ri;
  __syncthreads();
  for (int jj = 0; jj < 4; ++jj) {
    int j = jj*64 + c;
    float h = 0.f;
    for (int c2 = 0; c2 < 64; ++c2) h += s_g[c2] * wa[c2*256 + j];
    s_h[j] = h / (1.f + expf(-h));
  }
  __syncthreads();
  float acc = s_r[c];
  for (int j = 0; j < 256; ++j) acc += s_h[j] * wb[j*64 + c];
  stS(&f0[tok*64 + c], acc);
}

// ---------------- per-layer: vector FF ----------------
template<typename T>
__global__ __launch_bounds__(64) void k_ff1(T* f1, const float* w) {
  int tok = blockIdx.x, e = threadIdx.x;
  __shared__ float s_r[3][64], s_g[3][64];
  __shared__ float s_vs;
  for (int v = 0; v < 3; ++v) s_r[v][e] = ldS(&f1[(tok*3+v)*64 + e]);
  __syncthreads();
  if (e == 0) {
    float ss = 0.f;
    for (int c = 0; c < 64; ++c)
      ss += s_r[0][c]*s_r[0][c] + s_r[1][c]*s_r[1][c] + s_r[2][c]*s_r[2][c];
    s_vs = rsqrtf(ss*(1.f/64.f) + EPSF);
  }
  __syncthreads();
  for (int v = 0; v < 3; ++v) s_g[v][e] = s_r[v][e] * s_vs;
  __syncthreads();
  float acc[3];
  for (int v = 0; v < 3; ++v) acc[v] = s_r[v][e];
  for (int c = 0; c < 64; ++c) {
    float wv = w[c*64 + e];
    for (int v = 0; v < 3; ++v) acc[v] += s_g[v][c] * wv;
  }
  for (int v = 0; v < 3; ++v) stS(&f1[(tok*3+v)*64 + e], acc[v]);
}

// ---------------- final score (FLOAT32 output) ----------------
template<typename T>
__global__ __launch_bounds__(64) void k_final(const T* f1, const float* wout, const float* bout, float* out) {
  int tok = blockIdx.x, v = threadIdx.x;
  if (v < 3) {
    float acc = bout[v];
    for (int c = 0; c < 64; ++c) acc += ldS(&f1[(tok*3+v)*64 + c]) * wout[v*64 + c];
    out[tok*3 + v] = acc;
  }
}

template<typename T>
static void run_pipeline(const float** F, const int* nbr, const void* mask,
                         char* ws, float* out, hipStream_t stream) {
  int*   diag = (int*)ws;                       // 256 B
  float* te2  = (float*)(ws + 256);             // 2 KB
  float* rhat = (float*)(ws + 4096);            // 3 MB
  u16*   G0   = (u16*)(ws + 3149824);           // 8 MB
  u16*   G1   = (u16*)(ws + 11538432);          // 24 MB
  T*     f0   = (T*)(ws + 36704256);
  T*     f1   = f0 + (size_t)BN*64;
  const float *x=F[0], *t=F[1], *tw1=F[2], *tb1=F[3], *tw2=F[4], *tb2=F[5], *win1=F[6];
  const float *Wq0=F[7], *Wk0=F[8], *Wv0=F[9], *Wq1=F[10], *Wk1=F[11], *Wv1=F[12];
  const float *Wo0=F[13], *Wo1=F[14], *Wa=F[15], *Wb=F[16], *Wf1=F[17], *Wout=F[18], *Bout=F[19];

  k_check<<<1, 256, 0, stream>>>(nbr, mask, x, t, diag);
  k_te<<<1, 128, 0, stream>>>(t, tw1, tb1, tw2, tb2, te2);
  k_init<T><<<BN, 64, 0, stream>>>(x, win1, nbr, te2, f0, f1, rhat);
  for (int l = 0; l < LL; ++l) {
    k_norm<T><<<BN, 64, 0, stream>>>(f0, f1, G0, G1);
    k_attn<T><<<BN, 64, 0, stream>>>(G0, G1,
        Wq0 + l*4096, Wk0 + l*4096, Wv0 + l*4096,
        Wq1 + l*4096, Wk1 + l*4096, Wv1 + l*4096,
        Wo0 + l*4096, Wo1 + l*4096, nbr, rhat, f0, f1);
    k_ff0<T><<<BN, 64, 0, stream>>>(f0, Wa + l*16384, Wb + l*16384);
    k_ff1<T><<<BN, 64, 0, stream>>>(f1, Wf1 + l*4096);
  }
  k_final<T><<<BN, 64, 0, stream>>>(f1, Wout, Bout, out);
  k_guard<<<768, 256, 0, stream>>>(diag, out);
}

extern "C" void kernel_launch(void* const* d_in, const int* in_sizes, int n_in,
                              void* d_out, int out_size, void* d_ws, size_t ws_size,
                              hipStream_t stream) {
  float* out = (float*)d_out;
  static const int exp23[23] = {196608,196608,8,32768,32768,16384,128,7808,61,64,
                                16384,16384,16384,16384,16384,16384,16384,16384,
                                65536,65536,16384,192,3};
  bool ok23 = (n_in == 23), ok22 = (n_in == 22);
  int bad = -1;
  if (ok23) {
    for (int i = 0; i < 23; ++i) if (in_sizes[i] != exp23[i]) { ok23 = false; bad = i; break; }
  }
  if (!ok23 && ok22) {
    for (int i = 0; i < 22; ++i) {
      int want = (i == 0) ? exp23[0] : exp23[i+1];
      if (in_sizes[i] != want) { ok22 = false; if (bad < 0) bad = i; break; }
    }
  } else ok22 = false;
  if (!ok23 && !ok22) {
    k_const<<<768, 256, 0, stream>>>(out, (float)(3000 + (bad < 0 ? 100 + n_in : bad)));
    return;
  }
  int sh = ok23 ? 0 : -1;
  const int* nbr = (const int*)d_in[3 + sh];
  const void* mask = d_in[4 + sh];
  const float* F[20];
  F[0] = (const float*)d_in[0];
  F[1] = (const float*)d_in[2 + sh];
  for (int j = 0; j < 18; ++j) F[2 + j] = (const float*)d_in[5 + sh + j];

  const size_t need_f32  = 36704256 + (size_t)BN*256*4;
  const size_t need_bf16 = 36704256 + (size_t)BN*256*2;
  if (ws_size >= need_f32) {
    run_pipeline<float>(F, nbr, mask, (char*)d_ws, out, stream);
  } else if (ws_size >= need_bf16) {
    run_pipeline<u16>(F, nbr, mask, (char*)d_ws, out, stream);
  } else {
    unsigned mb = (unsigned)(ws_size >> 20);
    if (mb > 1500u) mb = 1500u;
    k_const<<<768, 256, 0, stream>>>(out, 50.0f + (float)mb);
  }
}

// Round 7
// 2230.860 us; speedup vs baseline: 2.1120x; 2.1120x over previous
//
#include <hip/hip_runtime.h>

#define BB 8
#define NN 8192
#define RR 2048
#define KK 4
#define LL 4
#define TC 61
#define EPSF 1e-6f
#define BN (BB*NN)
#define OUTN (BN*3)
#define TW 32
#define PP 36

typedef unsigned short u16;
typedef unsigned int u32;
typedef _Float16 h2f __attribute__((ext_vector_type(2)));

__device__ __forceinline__ float fd2(u32 a, u32 b, float acc) {
#if __has_builtin(__builtin_amdgcn_fdot2)
  return __builtin_amdgcn_fdot2(__builtin_bit_cast(h2f, a), __builtin_bit_cast(h2f, b), acc, false);
#else
  h2f A = __builtin_bit_cast(h2f, a), B = __builtin_bit_cast(h2f, b);
  return acc + (float)A.x * (float)B.x + (float)A.y * (float)B.y;
#endif
}
__device__ __forceinline__ u32 packf16(float a, float b) {
  h2f h; h.x = (_Float16)a; h.y = (_Float16)b; return __builtin_bit_cast(u32, h);
}
__device__ __forceinline__ u16 f16b(float a) {
  _Float16 h = (_Float16)a; return __builtin_bit_cast(u16, h);
}
__device__ __forceinline__ float2 unpk(u32 a) {
  h2f h = __builtin_bit_cast(h2f, a); return make_float2((float)h.x, (float)h.y);
}
__device__ __forceinline__ int kmax_of(int n) {
  int aatom = n & 3, rres = n >> 2;
  return (aatom==0) ? (rres==0 ? 2 : 3)
       : (aatom==1) ? 3
       : (aatom==2) ? (rres==RR-1 ? 3 : 4) : 2;
}

__global__ __launch_bounds__(256) void k_const(float* out, float v) {
  int i = blockIdx.x*256 + threadIdx.x;
  if (i < OUTN) out[i] = v;
}

// ---------- weight f16 pre-pack: 9 64x64-ish mats + ffa + ffb ----------
struct WSrc { const float* m[11]; };
__global__ __launch_bounds__(256) void k_prep(WSrc s, u32* W16) {
  int i = blockIdx.x*256 + threadIdx.x;   // 139264 items
  if (i < 73728) {                        // 9 matrices [64 x 64] per layer, pack over dim0
    int m = i >> 13, rr = i & 8191, l = rr >> 11, r2 = rr & 2047;
    int c2 = r2 >> 6, col = r2 & 63;
    const float* src = s.m[m] + l*4096;
    W16[i] = packf16(src[(2*c2)*64 + col], src[(2*c2+1)*64 + col]);
  } else if (i < 106496) {                // ffa [64 x 256], pack over c
    int j2 = i - 73728; int l = j2 >> 13, r2 = j2 & 8191;
    int c2 = r2 >> 8, j = r2 & 255;
    const float* src = s.m[9] + l*16384;
    W16[i] = packf16(src[(2*c2)*256 + j], src[(2*c2+1)*256 + j]);
  } else {                                // ffb [256 x 64], pack over j
    int j2 = i - 106496; int l = j2 >> 13, r2 = j2 & 8191;
    int jp = r2 >> 6, e = r2 & 63;
    const float* src = s.m[10] + l*16384;
    W16[i] = packf16(src[(2*jp)*64 + e], src[(2*jp+1)*64 + e]);
  }
}

// ---------- time embedding MLP ----------
__global__ __launch_bounds__(128) void k_te(const float* t, const float* w1, const float* b1,
                                            const float* w2, const float* b2, float* te2) {
  __shared__ float s0[128], s1[128];
  int j = threadIdx.x;
  for (int b = 0; b < BB; ++b) {
    float tv = t[b];
    int i = j & 63;
    float fr = expf(-9.210340371976184f * (float)i * (1.0f/64.0f));
    float em = tv * fr;
    s0[j] = (j < 64) ? sinf(em) : cosf(em);
    __syncthreads();
    float acc = b1[j];
    for (int i2 = 0; i2 < 128; ++i2) acc += s0[i2] * w1[i2*128 + j];
    s1[j] = acc / (1.f + expf(-acc));
    __syncthreads();
    if (j < TC) {
      float a2 = b2[j];
      for (int i2 = 0; i2 < 128; ++i2) a2 += s1[i2] * w2[i2*TC + j];
      te2[b*TC + j] = a2;
    }
    __syncthreads();
  }
}

// ---------- init f0/f1/rhat (wave per token) ----------
__global__ __launch_bounds__(256) void k_init(const float* x, const float* win1, const int* nbr,
                                              const float* te2, float* f0, float* f1, float* rhat) {
  int tok = blockIdx.x*4 + (threadIdx.x >> 6);
  int c = threadIdx.x & 63;
  int b = tok >> 13, n = tok & (NN-1);
  float x0 = x[tok*3+0], x1 = x[tok*3+1], x2 = x[tok*3+2];
  f0[tok*64 + c] = (c < TC) ? te2[b*TC + c] : (c == 61 ? x0 : (c == 62 ? x1 : x2));
  float wv = win1[c];
  f1[(tok*3+0)*64 + c] = x0 * wv;
  f1[(tok*3+1)*64 + c] = x1 * wv;
  f1[(tok*3+2)*64 + c] = x2 * wv;
  if (c < KK) {
    int tj = b*NN + nbr[n*KK + c];
    float rx = x[tj*3+0] - x0, ry = x[tj*3+1] - x1, rz = x[tj*3+2] - x2;
    float ir = rsqrtf(rx*rx + ry*ry + rz*rz + EPSF);
    rhat[(tok*KK+c)*3 + 0] = rx * ir;
    rhat[(tok*KK+c)*3 + 1] = ry * ir;
    rhat[(tok*KK+c)*3 + 2] = rz * ir;
  }
}

// ---------- fused layer: norm+QKV+attn+outproj+ff0+ff1 ----------
__global__ __launch_bounds__(256, 2) void k_layer(const u32* W16, int l,
    const int* nbr, const float* rhat, float* f0, float* f1) {
  __shared__ __align__(16) char SB[75776];
  u32* sg0 = (u32*)(SB);             // 36*32 packed f16 pairs (c)
  u32* sg1 = (u32*)(SB + 4608);      // 3*36*32
  u16* sk0 = (u16*)(SB + 18432);     // 36*64
  u16* sv0 = (u16*)(SB + 23040);
  u16* sk1 = (u16*)(SB + 27648);     // 3*36*64
  u16* sv1 = (u16*)(SB + 41472);
  u16* sq0 = (u16*)(SB + 55296);     // 32*64
  u16* sq1 = (u16*)(SB + 59392);     // 3*32*64
  float* srh = (float*)(SB + 71680); // 32*12
  float* sa  = (float*)(SB + 73216); // 32*4*4
  int*  spk  = (int*)(SB + 75264);   // 32*4
  // phase aliases (lifetimes disjoint, sync-separated)
  u32* so0   = (u32*)(SB);           // 32*32   (over sg0)
  u32* so1   = (u32*)(SB + 4608);    // 3*32*32 (over sg1)
  float* sf0n = (float*)(SB + 18432);// 32*64 f32 (over sk0+sv0)
  float* sf1n = (float*)(SB + 27648);// 3*32*64 f32 (over sk1+sv1)
  u32* sgf   = (u32*)(SB);           // 32*32 (over so0, after outproj)
  u32* sg1f  = (u32*)(SB + 4608);    // 3*32*32 (over so1)
  u16* sh    = (u16*)(SB + 55296);   // 32*256 (over sq0+sq1)

  const int tid = threadIdx.x;
  const int gb = blockIdx.x * TW;        // global token base (interior)
  const int nsin = gb & (NN-1);          // in-batch start
  const int bbase = gb - nsin;           // batch base token

  const u32 *pq0 = W16 + 0*8192 + l*2048, *pk0w = W16 + 1*8192 + l*2048, *pv0w = W16 + 2*8192 + l*2048;
  const u32 *pq1 = W16 + 3*8192 + l*2048, *pk1w = W16 + 4*8192 + l*2048, *pv1w = W16 + 5*8192 + l*2048;
  const u32 *po0 = W16 + 6*8192 + l*2048, *po1 = W16 + 7*8192 + l*2048, *pf1w = W16 + 8*8192 + l*2048;
  const u32 *pa = W16 + 73728 + l*8192, *pb = W16 + 106496 + l*8192;

  // ---- phase 1: LN/vnorm for 36 tokens (8-lane groups), pack f16 into LDS; stage rhat, nbr ----
  {
    int g = tid >> 3, ln = tid & 7;
    for (int p = g; p < PP; p += 32) {
      int nl = nsin + p - 2; nl = nl < 0 ? 0 : (nl > NN-1 ? NN-1 : nl);
      int tok = bbase + nl;
      float4 a0 = *(const float4*)(f0 + tok*64 + ln*8);
      float4 b0 = *(const float4*)(f0 + tok*64 + ln*8 + 4);
      float v0[8] = {a0.x,a0.y,a0.z,a0.w,b0.x,b0.y,b0.z,b0.w};
      float s = 0.f, s2 = 0.f, ss = 0.f;
#pragma unroll
      for (int i = 0; i < 8; ++i) { s += v0[i]; s2 += v0[i]*v0[i]; }
      float v1[24];
#pragma unroll
      for (int v = 0; v < 3; ++v) {
        float4 a1 = *(const float4*)(f1 + (tok*3+v)*64 + ln*8);
        float4 b1 = *(const float4*)(f1 + (tok*3+v)*64 + ln*8 + 4);
        v1[v*8+0]=a1.x; v1[v*8+1]=a1.y; v1[v*8+2]=a1.z; v1[v*8+3]=a1.w;
        v1[v*8+4]=b1.x; v1[v*8+5]=b1.y; v1[v*8+6]=b1.z; v1[v*8+7]=b1.w;
#pragma unroll
        for (int i = 0; i < 8; ++i) ss += v1[v*8+i]*v1[v*8+i];
      }
#pragma unroll
      for (int m = 1; m < 8; m <<= 1) {
        s  += __shfl_xor(s,  m, 64);
        s2 += __shfl_xor(s2, m, 64);
        ss += __shfl_xor(ss, m, 64);
      }
      float mu = s * (1.f/64.f);
      float ri = rsqrtf(fmaxf(s2*(1.f/64.f) - mu*mu, 0.f) + EPSF);
      float vs = rsqrtf(ss*(1.f/64.f) + EPSF);
#pragma unroll
      for (int i = 0; i < 4; ++i)
        sg0[p*32 + ln*4 + i] = packf16((v0[2*i]-mu)*ri, (v0[2*i+1]-mu)*ri);
#pragma unroll
      for (int v = 0; v < 3; ++v)
#pragma unroll
        for (int i = 0; i < 4; ++i)
          sg1[(v*PP+p)*32 + ln*4 + i] = packf16(v1[v*8+2*i]*vs, v1[v*8+2*i+1]*vs);
    }
    for (int i = tid; i < 384; i += 256) { int tk = i/12; srh[i] = rhat[(gb+tk)*12 + (i - tk*12)]; }
    if (tid < 128) {
      int tk = tid >> 2, k = tid & 3;
      int pv = nbr[(nsin+tk)*4 + k] - nsin + 2;
      spk[tid] = pv < 0 ? 0 : (pv > PP-1 ? PP-1 : pv);
    }
  }
  __syncthreads();

  // ---- phase 2: QKV projections (weight column in regs) ----
  {
    int e = tid & 63, grp = tid >> 6;
    u32 w[32];
#pragma unroll 8
    for (int c = 0; c < 32; ++c) w[c] = pq0[c*64+e];
    for (int tk = grp; tk < TW; tk += 4) {
      float acc = 0.f; const u32* g = sg0 + (tk+2)*32;
#pragma unroll
      for (int c = 0; c < 32; ++c) acc = fd2(g[c], w[c], acc);
      sq0[tk*64+e] = f16b(acc);
    }
#pragma unroll 8
    for (int c = 0; c < 32; ++c) w[c] = pk0w[c*64+e];
    for (int p = grp; p < PP; p += 4) {
      float acc = 0.f; const u32* g = sg0 + p*32;
#pragma unroll
      for (int c = 0; c < 32; ++c) acc = fd2(g[c], w[c], acc);
      sk0[p*64+e] = f16b(acc);
    }
#pragma unroll 8
    for (int c = 0; c < 32; ++c) w[c] = pv0w[c*64+e];
    for (int p = grp; p < PP; p += 4) {
      float acc = 0.f; const u32* g = sg0 + p*32;
#pragma unroll
      for (int c = 0; c < 32; ++c) acc = fd2(g[c], w[c], acc);
      sv0[p*64+e] = f16b(acc);
    }
#pragma unroll 8
    for (int c = 0; c < 32; ++c) w[c] = pq1[c*64+e];
    for (int i = grp; i < 96; i += 4) {
      int v = i >> 5, tk = i & 31;
      float acc = 0.f; const u32* g = sg1 + (v*PP + tk+2)*32;
#pragma unroll
      for (int c = 0; c < 32; ++c) acc = fd2(g[c], w[c], acc);
      sq1[(v*TW+tk)*64+e] = f16b(acc);
    }
#pragma unroll 8
    for (int c = 0; c < 32; ++c) w[c] = pk1w[c*64+e];
    for (int v = 0; v < 3; ++v)
      for (int p = grp; p < PP; p += 4) {
        float acc = 0.f; const u32* g = sg1 + (v*PP + p)*32;
#pragma unroll
        for (int c = 0; c < 32; ++c) acc = fd2(g[c], w[c], acc);
        sk1[(v*PP+p)*64+e] = f16b(acc);
      }
#pragma unroll 8
    for (int c = 0; c < 32; ++c) w[c] = pv1w[c*64+e];
    for (int v = 0; v < 3; ++v)
      for (int p = grp; p < PP; p += 4) {
        float acc = 0.f; const u32* g = sg1 + (v*PP + p)*32;
#pragma unroll
        for (int c = 0; c < 32; ++c) acc = fd2(g[c], w[c], acc);
        sv1[(v*PP+p)*64+e] = f16b(acc);
      }
  }
  __syncthreads();

  // ---- phase 3: QK^T logits ----
  for (int it = tid; it < 512; it += 256) {
    int tk = it >> 4, h = (it >> 2) & 3, k = it & 3;
    int pk = spk[tk*4+k];
    const u32* qp = (const u32*)sq0 + tk*32 + h*8;
    const u32* kp = (const u32*)sk0 + pk*32 + h*8;
    float acc = 0.f;
#pragma unroll
    for (int d = 0; d < 8; ++d) acc = fd2(qp[d], kp[d], acc);
#pragma unroll
    for (int v = 0; v < 3; ++v) {
      const u32* q1p = (const u32*)sq1 + (v*TW+tk)*32 + h*8;
      const u32* k1p = (const u32*)sk1 + (v*PP+pk)*32 + h*8;
#pragma unroll
      for (int d = 0; d < 8; ++d) acc = fd2(q1p[d], k1p[d], acc);
    }
    sa[it] = acc * 0.25f;
  }
  __syncthreads();

  // ---- phase 4: softmax over k (masked by structural kmax) ----
  if (tid < 128) {
    int tk = tid >> 2, h = tid & 3;
    int km = kmax_of(nsin + tk);
    float* row = sa + tk*16 + h*4;
    float mx = -1e30f;
    for (int k = 0; k < km; ++k) mx = fmaxf(mx, row[k]);
    float s = 0.f, aw[4];
#pragma unroll
    for (int k = 0; k < 4; ++k) { aw[k] = (k < km) ? expf(row[k]-mx) : 0.f; s += aw[k]; }
    float inv = 1.f / s;
#pragma unroll
    for (int k = 0; k < 4; ++k) row[k] = aw[k]*inv;
  }
  __syncthreads();

  // ---- phase 5: AV (with rhat cross terms), pack o to f16 ----
  for (int it = tid; it < 1024; it += 256) {
    int tk = it >> 5, ep = it & 31, h = ep >> 3;
    const float* arow = sa + tk*16 + h*4;
    float o0a=0,o0b=0,o1a[3]={0,0,0},o1b[3]={0,0,0};
#pragma unroll
    for (int k = 0; k < 4; ++k) {
      float a = arow[k];
      int pk = spk[tk*4+k];
      float2 v0 = unpk(((const u32*)sv0)[pk*32+ep]);
      float vx[3], vy[3];
#pragma unroll
      for (int v = 0; v < 3; ++v) {
        float2 t = unpk(((const u32*)sv1)[(v*PP+pk)*32+ep]);
        vx[v]=t.x; vy[v]=t.y;
      }
      const float* rh = srh + tk*12 + k*3;
      float vda = vx[0]*rh[0]+vx[1]*rh[1]+vx[2]*rh[2];
      float vdb = vy[0]*rh[0]+vy[1]*rh[1]+vy[2]*rh[2];
      o0a += a*(v0.x + vda); o0b += a*(v0.y + vdb);
#pragma unroll
      for (int v = 0; v < 3; ++v) {
        o1a[v] += a*(vx[v] + v0.x*rh[v]);
        o1b[v] += a*(vy[v] + v0.y*rh[v]);
      }
    }
    so0[tk*32+ep] = packf16(o0a, o0b);
#pragma unroll
    for (int v = 0; v < 3; ++v) so1[(v*TW+tk)*32+ep] = packf16(o1a[v], o1b[v]);
  }
  __syncthreads();

  // ---- phase 6: out-proj + residual into LDS f32 ----
  {
    int e = tid & 63, grp = tid >> 6;
    u32 w[32];
#pragma unroll 8
    for (int c = 0; c < 32; ++c) w[c] = po0[c*64+e];
    for (int tk = grp; tk < TW; tk += 4) {
      float acc = 0.f; const u32* o = so0 + tk*32;
#pragma unroll
      for (int c = 0; c < 32; ++c) acc = fd2(o[c], w[c], acc);
      sf0n[tk*64+e] = f0[(bbase+nsin+tk)*64+e] + acc;
    }
#pragma unroll 8
    for (int c = 0; c < 32; ++c) w[c] = po1[c*64+e];
    for (int i = grp; i < 96; i += 4) {
      int v = i >> 5, tk = i & 31;
      float acc = 0.f; const u32* o = so1 + (v*TW+tk)*32;
#pragma unroll
      for (int c = 0; c < 32; ++c) acc = fd2(o[c], w[c], acc);
      sf1n[(v*TW+tk)*64+e] = f1[((bbase+nsin+tk)*3+v)*64+e] + acc;
    }
  }
  __syncthreads();

  // ---- phase 7: ff0 LN + pack g ----
  {
    int g = tid >> 3, ln = tid & 7;
    float vv[8], s = 0.f, s2 = 0.f;
    const float* r = sf0n + g*64 + ln*8;
#pragma unroll
    for (int i = 0; i < 8; ++i) { float x = r[i]; vv[i] = x; s += x; s2 += x*x; }
#pragma unroll
    for (int m = 1; m < 8; m <<= 1) { s += __shfl_xor(s, m, 64); s2 += __shfl_xor(s2, m, 64); }
    float mu = s*(1.f/64.f);
    float ri = rsqrtf(fmaxf(s2*(1.f/64.f)-mu*mu, 0.f) + EPSF);
#pragma unroll
    for (int i = 0; i < 4; ++i)
      sgf[g*32 + ln*4 + i] = packf16((vv[2*i]-mu)*ri, (vv[2*i+1]-mu)*ri);
  }
  __syncthreads();

  // ---- phase 8: ff0 hidden (64->256) + silu ----
  {
    int j = tid;
    u32 w[32];
#pragma unroll 8
    for (int c = 0; c < 32; ++c) w[c] = pa[c*256+j];
    for (int tk = 0; tk < TW; ++tk) {
      float acc = 0.f; const u32* g = sgf + tk*32;
#pragma unroll
      for (int c = 0; c < 32; ++c) acc = fd2(g[c], w[c], acc);
      sh[tk*256+j] = f16b(acc / (1.f + expf(-acc)));
    }
  }
  __syncthreads();

  // ---- phase 9: ff0 out (256->64) + residual + write f0 ----
  {
    int e = tid & 63, grp = tid >> 6;
    float acc[8];
#pragma unroll
    for (int i = 0; i < 8; ++i) acc[i] = 0.f;
    u32 w[32];
    for (int ch = 0; ch < 4; ++ch) {
#pragma unroll 8
      for (int c = 0; c < 32; ++c) w[c] = pb[(ch*32+c)*64+e];
#pragma unroll
      for (int i = 0; i < 8; ++i) {
        int tk = grp + i*4;
        const u32* hp = (const u32*)sh + tk*128 + ch*32;
#pragma unroll
        for (int c = 0; c < 32; ++c) acc[i] = fd2(hp[c], w[c], acc[i]);
      }
    }
#pragma unroll
    for (int i = 0; i < 8; ++i) {
      int tk = grp + i*4;
      f0[(bbase+nsin+tk)*64+e] = sf0n[tk*64+e] + acc[i];
    }
  }
  // ---- phase 10: ff1 vnorm + pack (regions disjoint from phase 9) ----
  {
    int g = tid >> 3, ln = tid & 7;
    float vv[24], ss = 0.f;
#pragma unroll
    for (int v = 0; v < 3; ++v) {
      const float* r = sf1n + (v*TW+g)*64 + ln*8;
#pragma unroll
      for (int i = 0; i < 8; ++i) { float x = r[i]; vv[v*8+i] = x; ss += x*x; }
    }
#pragma unroll
    for (int m = 1; m < 8; m <<= 1) ss += __shfl_xor(ss, m, 64);
    float vs = rsqrtf(ss*(1.f/64.f) + EPSF);
#pragma unroll
    for (int v = 0; v < 3; ++v)
#pragma unroll
      for (int i = 0; i < 4; ++i)
        sg1f[(v*TW+g)*32 + ln*4 + i] = packf16(vv[v*8+2*i]*vs, vv[v*8+2*i+1]*vs);
  }
  __syncthreads();

  // ---- phase 11: ff1 out (64->64) + residual + write f1 ----
  {
    int e = tid & 63, grp = tid >> 6;
    u32 w[32];
#pragma unroll 8
    for (int c = 0; c < 32; ++c) w[c] = pf1w[c*64+e];
    for (int i = grp; i < 96; i += 4) {
      int v = i >> 5, tk = i & 31;
      float acc = 0.f; const u32* g = sg1f + (v*TW+tk)*32;
#pragma unroll
      for (int c = 0; c < 32; ++c) acc = fd2(g[c], w[c], acc);
      f1[((bbase+nsin+tk)*3+v)*64+e] = sf1n[(v*TW+tk)*64+e] + acc;
    }
  }
}

// ---------- final score (wave per token) ----------
__global__ __launch_bounds__(256) void k_final(const float* f1, const float* wout, const float* bout, float* out) {
  int tok = blockIdx.x*4 + (threadIdx.x >> 6);
  int lane = threadIdx.x & 63;
  float p[3];
#pragma unroll
  for (int v = 0; v < 3; ++v) {
    float x = f1[(tok*3+v)*64 + lane] * wout[v*64 + lane];
#pragma unroll
    for (int m = 1; m < 64; m <<= 1) x += __shfl_xor(x, m, 64);
    p[v] = x;
  }
  if (lane < 3) out[tok*3 + lane] = p[lane] + bout[lane];
}

extern "C" void kernel_launch(void* const* d_in, const int* in_sizes, int n_in,
                              void* d_out, int out_size, void* d_ws, size_t ws_size,
                              hipStream_t stream) {
  float* out = (float*)d_out;
  static const int exp23[23] = {196608,196608,8,32768,32768,16384,128,7808,61,64,
                                16384,16384,16384,16384,16384,16384,16384,16384,
                                65536,65536,16384,192,3};
  bool ok23 = (n_in == 23), ok22 = (n_in == 22);
  int bad = -1;
  if (ok23) {
    for (int i = 0; i < 23; ++i) if (in_sizes[i] != exp23[i]) { ok23 = false; bad = i; break; }
  }
  if (!ok23 && ok22) {
    for (int i = 0; i < 22; ++i) {
      int want = (i == 0) ? exp23[0] : exp23[i+1];
      if (in_sizes[i] != want) { ok22 = false; if (bad < 0) bad = i; break; }
    }
  } else ok22 = false;
  if (!ok23 && !ok22) {
    k_const<<<768, 256, 0, stream>>>(out, (float)(3000 + (bad < 0 ? 100 + n_in : bad)));
    return;
  }
  int sh = ok23 ? 0 : -1;
  const int* nbr = (const int*)d_in[3 + sh];
  const float* F[20];
  F[0] = (const float*)d_in[0];
  F[1] = (const float*)d_in[2 + sh];
  for (int j = 0; j < 18; ++j) F[2 + j] = (const float*)d_in[5 + sh + j];
  // F: 0 x, 1 t, 2 tw1, 3 tb1, 4 tw2, 5 tb2, 6 win1, 7 Wq0, 8 Wk0, 9 Wv0,
  //    10 Wq1, 11 Wk1, 12 Wv1, 13 Wo0, 14 Wo1, 15 Wff0a, 16 Wff0b, 17 Wff1, 18 Wout, 19 bout

  char* ws = (char*)d_ws;
  u32*   W16  = (u32*)ws;                         // 139264 u32 = 557056 B
  float* te2  = (float*)(ws + 557056);            // 2 KB
  float* rhat = (float*)(ws + 559104);            // BN*12*4 = 3145728
  float* f0   = (float*)(ws + 3704832);           // BN*64*4 = 16777216
  float* f1   = (float*)(ws + 20482048);          // BN*192*4 = 50331648 -> end ~70.8 MB

  WSrc s;
  s.m[0]=F[7]; s.m[1]=F[8]; s.m[2]=F[9]; s.m[3]=F[10]; s.m[4]=F[11]; s.m[5]=F[12];
  s.m[6]=F[13]; s.m[7]=F[14]; s.m[8]=F[17]; s.m[9]=F[15]; s.m[10]=F[16];

  k_prep<<<544, 256, 0, stream>>>(s, W16);
  k_te<<<1, 128, 0, stream>>>(F[1], F[2], F[3], F[4], F[5], te2);
  k_init<<<BN/4, 256, 0, stream>>>(F[0], F[6], nbr, te2, f0, f1, rhat);
  for (int l = 0; l < LL; ++l)
    k_layer<<<BN/TW, 256, 0, stream>>>(W16, l, nbr, rhat, f0, f1);
  k_final<<<BN/4, 256, 0, stream>>>(f1, F[18], F[19], out);
}

// Round 8
// 2107.152 us; speedup vs baseline: 2.2360x; 1.0587x over previous
//
#include <hip/hip_runtime.h>

#define BB 8
#define NN 8192
#define RR 2048
#define KK 4
#define LL 4
#define TC 61
#define EPSF 1e-6f
#define BN (BB*NN)
#define OUTN (BN*3)
#define TW 16
#define PP 20

typedef unsigned short u16;
typedef unsigned int u32;
typedef _Float16 h2f __attribute__((ext_vector_type(2)));

__device__ __forceinline__ float fd2(u32 a, u32 b, float acc) {
#if __has_builtin(__builtin_amdgcn_fdot2)
  return __builtin_amdgcn_fdot2(__builtin_bit_cast(h2f, a), __builtin_bit_cast(h2f, b), acc, false);
#else
  h2f A = __builtin_bit_cast(h2f, a), B = __builtin_bit_cast(h2f, b);
  return acc + (float)A.x * (float)B.x + (float)A.y * (float)B.y;
#endif
}
__device__ __forceinline__ float dot32(const u32* g, const u32* w) {
  float a0=0.f, a1=0.f, a2=0.f, a3=0.f;
#pragma unroll
  for (int c = 0; c < 32; c += 4) {
    a0 = fd2(g[c+0], w[c+0], a0);
    a1 = fd2(g[c+1], w[c+1], a1);
    a2 = fd2(g[c+2], w[c+2], a2);
    a3 = fd2(g[c+3], w[c+3], a3);
  }
  return (a0+a1)+(a2+a3);
}
__device__ __forceinline__ u32 packf16(float a, float b) {
  h2f h; h.x = (_Float16)a; h.y = (_Float16)b; return __builtin_bit_cast(u32, h);
}
__device__ __forceinline__ u16 f16b(float a) {
  _Float16 h = (_Float16)a; return __builtin_bit_cast(u16, h);
}
__device__ __forceinline__ float2 unpk(u32 a) {
  h2f h = __builtin_bit_cast(h2f, a); return make_float2((float)h.x, (float)h.y);
}
__device__ __forceinline__ int kmax_of(int n) {
  int aatom = n & 3, rres = n >> 2;
  return (aatom==0) ? (rres==0 ? 2 : 3)
       : (aatom==1) ? 3
       : (aatom==2) ? (rres==RR-1 ? 3 : 4) : 2;
}

__global__ __launch_bounds__(256) void k_const(float* out, float v) {
  int i = blockIdx.x*256 + threadIdx.x;
  if (i < OUTN) out[i] = v;
}

// ---------- weight f16 pre-pack ----------
struct WSrc { const float* m[11]; };
__global__ __launch_bounds__(256) void k_prep(WSrc s, u32* W16) {
  int i = blockIdx.x*256 + threadIdx.x;   // 139264 items
  if (i < 73728) {                        // 9 matrices [64 x 64] per layer, pack over dim0
    int m = i >> 13, rr = i & 8191, l = rr >> 11, r2 = rr & 2047;
    int c2 = r2 >> 6, col = r2 & 63;
    const float* src = s.m[m] + l*4096;
    W16[i] = packf16(src[(2*c2)*64 + col], src[(2*c2+1)*64 + col]);
  } else if (i < 106496) {                // ffa [64 x 256], pack over c
    int j2 = i - 73728; int l = j2 >> 13, r2 = j2 & 8191;
    int c2 = r2 >> 8, j = r2 & 255;
    const float* src = s.m[9] + l*16384;
    W16[i] = packf16(src[(2*c2)*256 + j], src[(2*c2+1)*256 + j]);
  } else {                                // ffb [256 x 64], pack over j
    int j2 = i - 106496; int l = j2 >> 13, r2 = j2 & 8191;
    int jp = r2 >> 6, e = r2 & 63;
    const float* src = s.m[10] + l*16384;
    W16[i] = packf16(src[(2*jp)*64 + e], src[(2*jp+1)*64 + e]);
  }
}

// ---------- time embedding MLP ----------
__global__ __launch_bounds__(128) void k_te(const float* t, const float* w1, const float* b1,
                                            const float* w2, const float* b2, float* te2) {
  __shared__ float s0[128], s1[128];
  int j = threadIdx.x;
  for (int b = 0; b < BB; ++b) {
    float tv = t[b];
    int i = j & 63;
    float fr = expf(-9.210340371976184f * (float)i * (1.0f/64.0f));
    float em = tv * fr;
    s0[j] = (j < 64) ? sinf(em) : cosf(em);
    __syncthreads();
    float acc = b1[j];
    for (int i2 = 0; i2 < 128; ++i2) acc += s0[i2] * w1[i2*128 + j];
    s1[j] = acc / (1.f + expf(-acc));
    __syncthreads();
    if (j < TC) {
      float a2 = b2[j];
      for (int i2 = 0; i2 < 128; ++i2) a2 += s1[i2] * w2[i2*TC + j];
      te2[b*TC + j] = a2;
    }
    __syncthreads();
  }
}

// ---------- init f0/f1/rhat ----------
__global__ __launch_bounds__(256) void k_init(const float* x, const float* win1, const int* nbr,
                                              const float* te2, float* f0, float* f1, float* rhat) {
  int tok = blockIdx.x*4 + (threadIdx.x >> 6);
  int c = threadIdx.x & 63;
  int b = tok >> 13, n = tok & (NN-1);
  float x0 = x[tok*3+0], x1 = x[tok*3+1], x2 = x[tok*3+2];
  f0[tok*64 + c] = (c < TC) ? te2[b*TC + c] : (c == 61 ? x0 : (c == 62 ? x1 : x2));
  float wv = win1[c];
  f1[(tok*3+0)*64 + c] = x0 * wv;
  f1[(tok*3+1)*64 + c] = x1 * wv;
  f1[(tok*3+2)*64 + c] = x2 * wv;
  if (c < KK) {
    int tj = b*NN + nbr[n*KK + c];
    float rx = x[tj*3+0] - x0, ry = x[tj*3+1] - x1, rz = x[tj*3+2] - x2;
    float ir = rsqrtf(rx*rx + ry*ry + rz*rz + EPSF);
    rhat[(tok*KK+c)*3 + 0] = rx * ir;
    rhat[(tok*KK+c)*3 + 1] = ry * ir;
    rhat[(tok*KK+c)*3 + 2] = rz * ir;
  }
}

// ---------- fused layer ----------
__global__ __launch_bounds__(256, 4) void k_layer(const u32* W16, int l,
    const int* nbr, const float* rhat, float* f0, float* f1) {
  __shared__ __align__(16) char SB[40960];
  u32* sg0 = (u32*)(SB);             // 20*32 u32 = 2560
  u32* sg1 = (u32*)(SB + 2560);      // 3*20*32 = 7680
  u16* sk0 = (u16*)(SB + 10240);     // 20*64 u16 = 2560
  u16* sv0 = (u16*)(SB + 12800);     // 2560
  u16* sk1 = (u16*)(SB + 15360);     // 3*20*64 = 7680
  u16* sv1 = (u16*)(SB + 23040);     // 7680
  u16* sq0 = (u16*)(SB + 30720);     // 16*64 = 2048
  u16* sq1 = (u16*)(SB + 32768);     // 3*16*64 = 6144
  float* srh = (float*)(SB + 38912); // 16*12 f32 = 768
  float* sa  = (float*)(SB + 39680); // 16*16 f32 = 1024
  int*  spk  = (int*)(SB + 40704);   // 16*4 = 256  -> total 40960
  // phase aliases (lifetimes disjoint, sync-separated)
  u32* so0   = (u32*)(SB);           // 16*32 = 2048 (over sg0)
  u32* so1   = (u32*)(SB + 2560);    // 3*16*32 = 6144 (over sg1)
  float* sf0n = (float*)(SB + 10240);// 16*64 f32 = 4096 (over sk0/sv0)
  float* sf1n = (float*)(SB + 15360);// 3*16*64 f32 = 12288 (over sk1/sv1)
  u32* sgf   = (u32*)(SB);           // 2048 (over so0)
  u32* sg1f  = (u32*)(SB + 2560);    // 6144 (over so1)
  u16* sh    = (u16*)(SB + 30720);   // 16*256 u16 = 8192 (over sq0+sq1)

  const int tid = threadIdx.x;
  const int gb = blockIdx.x * TW;
  const int nsin = gb & (NN-1);
  const int bbase = gb - nsin;

  const u32 *pq0 = W16 + 0*8192 + l*2048, *pk0w = W16 + 1*8192 + l*2048, *pv0w = W16 + 2*8192 + l*2048;
  const u32 *pq1 = W16 + 3*8192 + l*2048, *pk1w = W16 + 4*8192 + l*2048, *pv1w = W16 + 5*8192 + l*2048;
  const u32 *po0 = W16 + 6*8192 + l*2048, *po1 = W16 + 7*8192 + l*2048, *pf1w = W16 + 8*8192 + l*2048;
  const u32 *pa = W16 + 73728 + l*8192, *pb = W16 + 106496 + l*8192;

  // ---- phase 1: LN/vnorm for PP tokens (8-lane groups), pack f16; stage rhat, nbr ----
  {
    int g = tid >> 3, ln = tid & 7;
    if (g < PP) {
      int p = g;
      int nl = nsin + p - 2; nl = nl < 0 ? 0 : (nl > NN-1 ? NN-1 : nl);
      int tok = bbase + nl;
      float4 a0 = *(const float4*)(f0 + tok*64 + ln*8);
      float4 b0 = *(const float4*)(f0 + tok*64 + ln*8 + 4);
      float v0[8] = {a0.x,a0.y,a0.z,a0.w,b0.x,b0.y,b0.z,b0.w};
      float s = 0.f, s2 = 0.f, ss = 0.f;
#pragma unroll
      for (int i = 0; i < 8; ++i) { s += v0[i]; s2 += v0[i]*v0[i]; }
      float v1[24];
#pragma unroll
      for (int v = 0; v < 3; ++v) {
        float4 a1 = *(const float4*)(f1 + (tok*3+v)*64 + ln*8);
        float4 b1 = *(const float4*)(f1 + (tok*3+v)*64 + ln*8 + 4);
        v1[v*8+0]=a1.x; v1[v*8+1]=a1.y; v1[v*8+2]=a1.z; v1[v*8+3]=a1.w;
        v1[v*8+4]=b1.x; v1[v*8+5]=b1.y; v1[v*8+6]=b1.z; v1[v*8+7]=b1.w;
#pragma unroll
        for (int i = 0; i < 8; ++i) ss += v1[v*8+i]*v1[v*8+i];
      }
#pragma unroll
      for (int m = 1; m < 8; m <<= 1) {
        s  += __shfl_xor(s,  m, 64);
        s2 += __shfl_xor(s2, m, 64);
        ss += __shfl_xor(ss, m, 64);
      }
      float mu = s * (1.f/64.f);
      float ri = rsqrtf(fmaxf(s2*(1.f/64.f) - mu*mu, 0.f) + EPSF);
      float vs = rsqrtf(ss*(1.f/64.f) + EPSF);
#pragma unroll
      for (int i = 0; i < 4; ++i)
        sg0[p*32 + ln*4 + i] = packf16((v0[2*i]-mu)*ri, (v0[2*i+1]-mu)*ri);
#pragma unroll
      for (int v = 0; v < 3; ++v)
#pragma unroll
        for (int i = 0; i < 4; ++i)
          sg1[(v*PP+p)*32 + ln*4 + i] = packf16(v1[v*8+2*i]*vs, v1[v*8+2*i+1]*vs);
    }
    if (tid < 192) { int tk = tid/12; srh[tid] = rhat[(gb+tk)*12 + (tid - tk*12)]; }
    if (tid < 64) {
      int tk = tid >> 2, k = tid & 3;
      int pv = nbr[(nsin+tk)*4 + k] - nsin + 2;
      spk[tid] = pv < 0 ? 0 : (pv > PP-1 ? PP-1 : pv);
    }
  }
  __syncthreads();

  // ---- phase 2: QKV projections (weight column in regs) ----
  {
    int e = tid & 63, grp = tid >> 6;
    u32 w[32];
#pragma unroll 8
    for (int c = 0; c < 32; ++c) w[c] = pq0[c*64+e];
    for (int tk = grp; tk < TW; tk += 4)
      sq0[tk*64+e] = f16b(dot32(sg0 + (tk+2)*32, w));
#pragma unroll 8
    for (int c = 0; c < 32; ++c) w[c] = pk0w[c*64+e];
    for (int p = grp; p < PP; p += 4)
      sk0[p*64+e] = f16b(dot32(sg0 + p*32, w));
#pragma unroll 8
    for (int c = 0; c < 32; ++c) w[c] = pv0w[c*64+e];
    for (int p = grp; p < PP; p += 4)
      sv0[p*64+e] = f16b(dot32(sg0 + p*32, w));
#pragma unroll 8
    for (int c = 0; c < 32; ++c) w[c] = pq1[c*64+e];
    for (int i = grp; i < 3*TW; i += 4) {
      int v = i >> 4, tk = i & 15;
      sq1[(v*TW+tk)*64+e] = f16b(dot32(sg1 + (v*PP + tk+2)*32, w));
    }
#pragma unroll 8
    for (int c = 0; c < 32; ++c) w[c] = pk1w[c*64+e];
    for (int v = 0; v < 3; ++v)
      for (int p = grp; p < PP; p += 4)
        sk1[(v*PP+p)*64+e] = f16b(dot32(sg1 + (v*PP + p)*32, w));
#pragma unroll 8
    for (int c = 0; c < 32; ++c) w[c] = pv1w[c*64+e];
    for (int v = 0; v < 3; ++v)
      for (int p = grp; p < PP; p += 4)
        sv1[(v*PP+p)*64+e] = f16b(dot32(sg1 + (v*PP + p)*32, w));
  }
  __syncthreads();

  // ---- phase 3: QK^T logits (one per thread: 16 tok x 4 h x 4 k) ----
  {
    int it = tid;
    int tk = it >> 4, h = (it >> 2) & 3, k = it & 3;
    int pk = spk[tk*4+k];
    const u32* qp = (const u32*)sq0 + tk*32 + h*8;
    const u32* kp = (const u32*)sk0 + pk*32 + h*8;
    float acc0 = 0.f, acc1 = 0.f;
#pragma unroll
    for (int d = 0; d < 8; d += 2) {
      acc0 = fd2(qp[d],   kp[d],   acc0);
      acc1 = fd2(qp[d+1], kp[d+1], acc1);
    }
#pragma unroll
    for (int v = 0; v < 3; ++v) {
      const u32* q1p = (const u32*)sq1 + (v*TW+tk)*32 + h*8;
      const u32* k1p = (const u32*)sk1 + (v*PP+pk)*32 + h*8;
#pragma unroll
      for (int d = 0; d < 8; d += 2) {
        acc0 = fd2(q1p[d],   k1p[d],   acc0);
        acc1 = fd2(q1p[d+1], k1p[d+1], acc1);
      }
    }
    sa[it] = (acc0 + acc1) * 0.25f;
  }
  __syncthreads();

  // ---- phase 4: softmax ----
  if (tid < 64) {
    int tk = tid >> 2, h = tid & 3;
    int km = kmax_of(nsin + tk);
    float* row = sa + tk*16 + h*4;
    float mx = -1e30f;
    for (int k = 0; k < km; ++k) mx = fmaxf(mx, row[k]);
    float s = 0.f, aw[4];
#pragma unroll
    for (int k = 0; k < 4; ++k) { aw[k] = (k < km) ? expf(row[k]-mx) : 0.f; s += aw[k]; }
    float inv = 1.f / s;
#pragma unroll
    for (int k = 0; k < 4; ++k) row[k] = aw[k]*inv;
  }
  __syncthreads();

  // ---- phase 5: AV ----
  for (int it = tid; it < TW*32; it += 256) {
    int tk = it >> 5, ep = it & 31, h = ep >> 3;
    const float* arow = sa + tk*16 + h*4;
    float o0a=0,o0b=0,o1a[3]={0,0,0},o1b[3]={0,0,0};
#pragma unroll
    for (int k = 0; k < 4; ++k) {
      float a = arow[k];
      int pk = spk[tk*4+k];
      float2 v0 = unpk(((const u32*)sv0)[pk*32+ep]);
      float vx[3], vy[3];
#pragma unroll
      for (int v = 0; v < 3; ++v) {
        float2 t = unpk(((const u32*)sv1)[(v*PP+pk)*32+ep]);
        vx[v]=t.x; vy[v]=t.y;
      }
      const float* rh = srh + tk*12 + k*3;
      float vda = vx[0]*rh[0]+vx[1]*rh[1]+vx[2]*rh[2];
      float vdb = vy[0]*rh[0]+vy[1]*rh[1]+vy[2]*rh[2];
      o0a += a*(v0.x + vda); o0b += a*(v0.y + vdb);
#pragma unroll
      for (int v = 0; v < 3; ++v) {
        o1a[v] += a*(vx[v] + v0.x*rh[v]);
        o1b[v] += a*(vy[v] + v0.y*rh[v]);
      }
    }
    so0[tk*32+ep] = packf16(o0a, o0b);
#pragma unroll
    for (int v = 0; v < 3; ++v) so1[(v*TW+tk)*32+ep] = packf16(o1a[v], o1b[v]);
  }
  __syncthreads();

  // ---- phase 6: out-proj + residual into LDS f32 ----
  {
    int e = tid & 63, grp = tid >> 6;
    u32 w[32];
#pragma unroll 8
    for (int c = 0; c < 32; ++c) w[c] = po0[c*64+e];
    for (int tk = grp; tk < TW; tk += 4)
      sf0n[tk*64+e] = f0[(bbase+nsin+tk)*64+e] + dot32(so0 + tk*32, w);
#pragma unroll 8
    for (int c = 0; c < 32; ++c) w[c] = po1[c*64+e];
    for (int i = grp; i < 3*TW; i += 4) {
      int v = i >> 4, tk = i & 15;
      sf1n[(v*TW+tk)*64+e] = f1[((bbase+nsin+tk)*3+v)*64+e] + dot32(so1 + (v*TW+tk)*32, w);
    }
  }
  __syncthreads();

  // ---- phase 7: ff0 LN + pack g ----
  {
    int g = tid >> 3, ln = tid & 7;
    if (g < TW) {
      float vv[8], s = 0.f, s2 = 0.f;
      const float* r = sf0n + g*64 + ln*8;
#pragma unroll
      for (int i = 0; i < 8; ++i) { float x = r[i]; vv[i] = x; s += x; s2 += x*x; }
#pragma unroll
      for (int m = 1; m < 8; m <<= 1) { s += __shfl_xor(s, m, 64); s2 += __shfl_xor(s2, m, 64); }
      float mu = s*(1.f/64.f);
      float ri = rsqrtf(fmaxf(s2*(1.f/64.f)-mu*mu, 0.f) + EPSF);
#pragma unroll
      for (int i = 0; i < 4; ++i)
        sgf[g*32 + ln*4 + i] = packf16((vv[2*i]-mu)*ri, (vv[2*i+1]-mu)*ri);
    }
  }
  __syncthreads();

  // ---- phase 8: ff0 hidden (64->256) + silu ----
  {
    int j = tid;
    u32 w[32];
#pragma unroll 8
    for (int c = 0; c < 32; ++c) w[c] = pa[c*256+j];
#pragma unroll 2
    for (int tk = 0; tk < TW; ++tk) {
      float acc = dot32(sgf + tk*32, w);
      sh[tk*256+j] = f16b(acc / (1.f + expf(-acc)));
    }
  }
  __syncthreads();

  // ---- phase 9: ff0 out (256->64) + residual + write f0 ----
  {
    int e = tid & 63, grp = tid >> 6;
    float acc[4];
#pragma unroll
    for (int i = 0; i < 4; ++i) acc[i] = 0.f;
    u32 w[32];
    for (int ch = 0; ch < 4; ++ch) {
#pragma unroll 8
      for (int c = 0; c < 32; ++c) w[c] = pb[(ch*32+c)*64+e];
#pragma unroll
      for (int i = 0; i < 4; ++i) {
        int tk = grp + i*4;
        acc[i] += dot32((const u32*)sh + tk*128 + ch*32, w);
      }
    }
#pragma unroll
    for (int i = 0; i < 4; ++i) {
      int tk = grp + i*4;
      f0[(bbase+nsin+tk)*64+e] = sf0n[tk*64+e] + acc[i];
    }
  }
  // ---- phase 10: ff1 vnorm + pack (regions disjoint from phase 9) ----
  {
    int g = tid >> 3, ln = tid & 7;
    if (g < TW) {
      float vv[24], ss = 0.f;
#pragma unroll
      for (int v = 0; v < 3; ++v) {
        const float* r = sf1n + (v*TW+g)*64 + ln*8;
#pragma unroll
        for (int i = 0; i < 8; ++i) { float x = r[i]; vv[v*8+i] = x; ss += x*x; }
      }
#pragma unroll
      for (int m = 1; m < 8; m <<= 1) ss += __shfl_xor(ss, m, 64);
      float vs = rsqrtf(ss*(1.f/64.f) + EPSF);
#pragma unroll
      for (int v = 0; v < 3; ++v)
#pragma unroll
        for (int i = 0; i < 4; ++i)
          sg1f[(v*TW+g)*32 + ln*4 + i] = packf16(vv[v*8+2*i]*vs, vv[v*8+2*i+1]*vs);
    }
  }
  __syncthreads();

  // ---- phase 11: ff1 out (64->64) + residual + write f1 ----
  {
    int e = tid & 63, grp = tid >> 6;
    u32 w[32];
#pragma unroll 8
    for (int c = 0; c < 32; ++c) w[c] = pf1w[c*64+e];
    for (int i = grp; i < 3*TW; i += 4) {
      int v = i >> 4, tk = i & 15;
      f1[((bbase+nsin+tk)*3+v)*64+e] = sf1n[(v*TW+tk)*64+e] + dot32(sg1f + (v*TW+tk)*32, w);
    }
  }
}

// ---------- final score ----------
__global__ __launch_bounds__(256) void k_final(const float* f1, const float* wout, const float* bout, float* out) {
  int tok = blockIdx.x*4 + (threadIdx.x >> 6);
  int lane = threadIdx.x & 63;
  float p[3];
#pragma unroll
  for (int v = 0; v < 3; ++v) {
    float x = f1[(tok*3+v)*64 + lane] * wout[v*64 + lane];
#pragma unroll
    for (int m = 1; m < 64; m <<= 1) x += __shfl_xor(x, m, 64);
    p[v] = x;
  }
  if (lane < 3) out[tok*3 + lane] = p[lane] + bout[lane];
}

extern "C" void kernel_launch(void* const* d_in, const int* in_sizes, int n_in,
                              void* d_out, int out_size, void* d_ws, size_t ws_size,
                              hipStream_t stream) {
  float* out = (float*)d_out;
  static const int exp23[23] = {196608,196608,8,32768,32768,16384,128,7808,61,64,
                                16384,16384,16384,16384,16384,16384,16384,16384,
                                65536,65536,16384,192,3};
  bool ok23 = (n_in == 23), ok22 = (n_in == 22);
  int bad = -1;
  if (ok23) {
    for (int i = 0; i < 23; ++i) if (in_sizes[i] != exp23[i]) { ok23 = false; bad = i; break; }
  }
  if (!ok23 && ok22) {
    for (int i = 0; i < 22; ++i) {
      int want = (i == 0) ? exp23[0] : exp23[i+1];
      if (in_sizes[i] != want) { ok22 = false; if (bad < 0) bad = i; break; }
    }
  } else ok22 = false;
  if (!ok23 && !ok22) {
    k_const<<<768, 256, 0, stream>>>(out, (float)(3000 + (bad < 0 ? 100 + n_in : bad)));
    return;
  }
  int sh = ok23 ? 0 : -1;
  const int* nbr = (const int*)d_in[3 + sh];
  const float* F[20];
  F[0] = (const float*)d_in[0];
  F[1] = (const float*)d_in[2 + sh];
  for (int j = 0; j < 18; ++j) F[2 + j] = (const float*)d_in[5 + sh + j];

  char* ws = (char*)d_ws;
  u32*   W16  = (u32*)ws;                         // 557056 B
  float* te2  = (float*)(ws + 557056);
  float* rhat = (float*)(ws + 559104);
  float* f0   = (float*)(ws + 3704832);
  float* f1   = (float*)(ws + 20482048);

  WSrc s;
  s.m[0]=F[7]; s.m[1]=F[8]; s.m[2]=F[9]; s.m[3]=F[10]; s.m[4]=F[11]; s.m[5]=F[12];
  s.m[6]=F[13]; s.m[7]=F[14]; s.m[8]=F[17]; s.m[9]=F[15]; s.m[10]=F[16];

  k_prep<<<544, 256, 0, stream>>>(s, W16);
  k_te<<<1, 128, 0, stream>>>(F[1], F[2], F[3], F[4], F[5], te2);
  k_init<<<BN/4, 256, 0, stream>>>(F[0], F[6], nbr, te2, f0, f1, rhat);
  for (int l = 0; l < LL; ++l)
    k_layer<<<BN/TW, 256, 0, stream>>>(W16, l, nbr, rhat, f0, f1);
  k_final<<<BN/4, 256, 0, stream>>>(f1, F[18], F[19], out);
}